// Round 2
// baseline (171.619 us; speedup 1.0000x reference)
//
#include <hip/hip_runtime.h>
#include <cstdint>

typedef _Float16 f16;
typedef _Float16 f16x4 __attribute__((ext_vector_type(4)));
typedef _Float16 f16x8 __attribute__((ext_vector_type(8)));
typedef float f32x4 __attribute__((ext_vector_type(4)));

#define AS1U const __attribute__((address_space(1))) unsigned int
#define AS3U __attribute__((address_space(3))) unsigned int

__device__ __forceinline__ void gload_lds16(const void* g, void* l) {
    __builtin_amdgcn_global_load_lds((AS1U*)g, (AS3U*)l, 16, 0, 0);
}

// wave-local LDS sync: HGCN reduction state is per-wave (64 lanes, lockstep)
#define WSYNC() asm volatile("s_waitcnt lgkmcnt(0)" ::: "memory")

#define BATCH 16384
#define NAG   32
#define OBS   96
#define SDIM  1024
#define NE    64
#define HIDN  256
#define NH    1024

#define NB_PW   256
#define NB_SM   101
#define NB_PREP (NB_PW + NB_SM)

#define NB_GEMM 1024
#define NB_HG   4096
#define NB_MAIN 5120      // interleaved 1:4 (bid%5==0 -> GEMM)

// ======================= K_PREP: weight packs only =======================
__global__ __launch_bounds__(256) void k_prep(
    const float* __restrict__ w1a, const float* __restrict__ w1b,
    const float* __restrict__ w1c, const float* __restrict__ w1d,
    const float* __restrict__ b1a, const float* __restrict__ b1b,
    const float* __restrict__ b1c, const float* __restrict__ b1d,
    const float* __restrict__ w2a, const float* __restrict__ w2b,
    const float* __restrict__ w2c, const float* __restrict__ w2d,
    f16* __restrict__ W1t, float* __restrict__ b1cat,
    f16* __restrict__ W2t, f16* __restrict__ hcw2) {
    __shared__ float tile[64 * 65];
    const int tid = threadIdx.x;
    int bid = blockIdx.x;

    if (bid < NB_PW) {                    // W1 pack via LDS transpose
        int mlp = bid >> 6, rem = bid & 63, kt = rem >> 2, ct = rem & 3;
        const float* src = (mlp == 0) ? w1a : (mlp == 1) ? w1b : (mlp == 2) ? w1c : w1d;
        int k0 = kt * 64, c0 = ct * 64;
        for (int i = tid; i < 4096; i += 256) {
            int kk = i >> 6, cc = i & 63;
            tile[kk * 65 + cc] = src[(size_t)(k0 + kk) * 256 + c0 + cc];
        }
        __syncthreads();
        for (int i = tid; i < 4096; i += 256) {
            int cc = i >> 6, kk = i & 63;
            W1t[(size_t)(mlp * 256 + c0 + cc) * 1024 + k0 + kk] = (f16)tile[kk * 65 + cc];
        }
        return;
    }
    bid -= NB_PW;
    int i = bid * 256 + tid;
    if (i < 24576) {                      // W2t[p][o][k] = W2_p[k][o]
        int mp = i >> 13, rem = i & 8191, oo = rem >> 8, kk = rem & 255;
        const float* src = (mp == 0) ? w2a : (mp == 1) ? w2b : w2c;
        W2t[i] = (f16)src[kk * 32 + oo];
    } else if (i < 24832) {
        int k = i - 24576;
        hcw2[k] = (f16)w2d[k];
    } else {                              // i < 25856 : b1cat
        int n = i - 24832;
        int mlp = n >> 8, c = n & 255;
        const float* bsrc = (mlp == 0) ? b1a : (mlp == 1) ? b1b : (mlp == 2) ? b1c : b1d;
        b1cat[n] = bsrc[c];
    }
}

// ======================= K_MAIN: GEMM (1/5) + HGCN (4/5) co-resident =======================
__global__ __launch_bounds__(256) void k_main(
    const float* __restrict__ agent_qs, const float* __restrict__ states,
    const float* __restrict__ indiv_us, const float* __restrict__ edge_W,
    const float* __restrict__ edge_b, const float* __restrict__ wline1,
    const float* __restrict__ wline2,
    const f16* __restrict__ W1t, const float* __restrict__ b1cat,
    const f16* __restrict__ W2t, const f16* __restrict__ hcw2,
    float* __restrict__ qs_tot, float* __restrict__ Pp) {
    __shared__ __align__(16) char arena[50688];
    const int tid = threadIdx.x;
    const int bid = blockIdx.x;
    const int w = tid >> 6, l = tid & 63;
    const int lm = l & 15, lk = l >> 4;

    if (bid % 5 == 0) {
        // ---------------- GEMM: hid = relu(states @ W1t^T + b1) ; fused layer-2 partials ----------------
        f16* As = (f16*)arena;                 // [128][64] f16, XOR-swizzled chunks
        f16* Bs = (f16*)(arena + 16384);       // [128][64] f16, XOR-swizzled chunks
        f16* Ts = (f16*)arena;                 // [128][132] relu'd tile (after K-loop)

        const int g = bid / 5;
        const int xcd = bid & 7;               // bid round-robins XCDs; bid=5g hits all 8 per 8 g's
        const int slot = g >> 3;               // 0..127
        const int region = slot >> 5;          // 0..3   (A 2MB fp32 + B 2MB f16 = 4MB = one XCD L2)
        const int rs = slot & 31;
        const int mt = (xcd * 4 + region) * 4 + (rs >> 3);   // 0..127
        const int nt = rs & 7;
        const int m0 = mt * 128, n0 = nt * 128;
        const int wm = w >> 1, wn = w & 1;
        const int srow = l >> 3, schunk = l & 7;
        const int gchunk = schunk ^ srow;      // pre-swizzled global source for gload_lds

        f32x4 acc[4][4];
        #pragma unroll
        for (int i = 0; i < 4; i++)
            #pragma unroll
            for (int j = 0; j < 4; j++) acc[i][j] = (f32x4){0.f, 0.f, 0.f, 0.f};

        for (int kt = 0; kt < 16; kt++) {
            // B: f16 direct-to-LDS, source pre-swizzled so linear dest == swizzled layout
            #pragma unroll
            for (int i = 0; i < 4; i++) {
                int c = w * 4 + i;
                int row = c * 8 + srow;
                gload_lds16(&W1t[(size_t)(n0 + row) * 1024 + kt * 64 + gchunk * 8], &Bs[c * 512]);
            }
            // A: fp32 global -> f16 regs -> swizzled ds_write (no states16 pass)
            #pragma unroll
            for (int i = 0; i < 4; i++) {
                int idx = i * 256 + tid;
                int row = idx >> 3, ch = idx & 7;
                const float* src = &states[(size_t)(m0 + row) * 1024 + kt * 64 + ch * 8];
                float4 v0 = *(const float4*)src;
                float4 v1 = *(const float4*)(src + 4);
                f16x8 hv = { (f16)v0.x, (f16)v0.y, (f16)v0.z, (f16)v0.w,
                             (f16)v1.x, (f16)v1.y, (f16)v1.z, (f16)v1.w };
                *(f16x8*)&As[row * 64 + ((ch ^ (row & 7)) << 3)] = hv;
            }
            __syncthreads();
            #pragma unroll
            for (int ks = 0; ks < 2; ks++) {
                const int sw = ((ks * 4 + lk) ^ (lm & 7)) << 3;
                f16x8 a[4], bb[4];
                #pragma unroll
                for (int i = 0; i < 4; i++)
                    a[i] = *(const f16x8*)&As[(wm * 64 + i * 16 + lm) * 64 + sw];
                #pragma unroll
                for (int j = 0; j < 4; j++)
                    bb[j] = *(const f16x8*)&Bs[(wn * 64 + j * 16 + lm) * 64 + sw];
                #pragma unroll
                for (int i = 0; i < 4; i++)
                    #pragma unroll
                    for (int j = 0; j < 4; j++)
                        acc[i][j] = __builtin_amdgcn_mfma_f32_16x16x32_f16(a[i], bb[j], acc[i][j], 0, 0, 0);
            }
            __syncthreads();
        }

        // bias + relu -> Ts (f16), C-layout scatter
        float bj[4];
        #pragma unroll
        for (int j = 0; j < 4; j++) bj[j] = b1cat[n0 + wn * 64 + j * 16 + lm];
        #pragma unroll
        for (int i = 0; i < 4; i++)
            #pragma unroll
            for (int r = 0; r < 4; r++) {
                int row = wm * 64 + i * 16 + lk * 4 + r;
                #pragma unroll
                for (int j = 0; j < 4; j++) {
                    int col = wn * 64 + j * 16 + lm;
                    float v = acc[i][j][r] + bj[j];
                    Ts[row * 132 + col] = (f16)(v > 0.f ? v : 0.f);
                }
            }
        __syncthreads();

        // fused layer-2 K-half partial: this block's 128 cols = half of MLP (nt>>1)'s K=256
        const int mlp = nt >> 1, kh = nt & 1;
        const int rbase = w * 32;
        if (mlp < 3) {
            const f16* wb = W2t + mlp * 8192 + kh * 128;
            f32x4 acc2[2][2];
            acc2[0][0] = (f32x4){0,0,0,0}; acc2[0][1] = (f32x4){0,0,0,0};
            acc2[1][0] = (f32x4){0,0,0,0}; acc2[1][1] = (f32x4){0,0,0,0};
            #pragma unroll
            for (int ks = 0; ks < 4; ks++) {
                f16x8 b0 = *(const f16x8*)&wb[lm * 256 + ks * 32 + lk * 8];
                f16x8 b1 = *(const f16x8*)&wb[(16 + lm) * 256 + ks * 32 + lk * 8];
                #pragma unroll
                for (int i2 = 0; i2 < 2; i2++) {
                    f16x8 a = *(const f16x8*)&Ts[(rbase + i2 * 16 + lm) * 132 + ks * 32 + lk * 8];
                    acc2[i2][0] = __builtin_amdgcn_mfma_f32_16x16x32_f16(a, b0, acc2[i2][0], 0, 0, 0);
                    acc2[i2][1] = __builtin_amdgcn_mfma_f32_16x16x32_f16(a, b1, acc2[i2][1], 0, 0, 0);
                }
            }
            #pragma unroll
            for (int i2 = 0; i2 < 2; i2++)
                #pragma unroll
                for (int j2 = 0; j2 < 2; j2++)
                    #pragma unroll
                    for (int r = 0; r < 4; r++)
                        Pp[((size_t)kh * BATCH + m0 + rbase + i2 * 16 + lk * 4 + r) * 104
                           + mlp * 32 + j2 * 16 + lm] = acc2[i2][j2][r];
        } else {
            const f16* hc = hcw2 + kh * 128;
            f32x4 acc2[2];
            acc2[0] = (f32x4){0,0,0,0}; acc2[1] = (f32x4){0,0,0,0};
            #pragma unroll
            for (int ks = 0; ks < 4; ks++) {
                f16x8 bz = (f16x8){0,0,0,0,0,0,0,0};
                if (lm == 0) bz = *(const f16x8*)&hc[ks * 32 + lk * 8];
                #pragma unroll
                for (int i2 = 0; i2 < 2; i2++) {
                    f16x8 a = *(const f16x8*)&Ts[(rbase + i2 * 16 + lm) * 132 + ks * 32 + lk * 8];
                    acc2[i2] = __builtin_amdgcn_mfma_f32_16x16x32_f16(a, bz, acc2[i2], 0, 0, 0);
                }
            }
            if (lm == 0)
                #pragma unroll
                for (int i2 = 0; i2 < 2; i2++)
                    #pragma unroll
                    for (int r = 0; r < 4; r++)
                        Pp[((size_t)kh * BATCH + m0 + rbase + i2 * 16 + lk * 4 + r) * 104 + 96]
                            = acc2[i2][r];
        }
        return;
    }

    // ---------------- HGCN ----------------
    f16*   eWs   = (f16*)arena;                 // 64*104 f16 = 13312 B
    float* swa   = (float*)(arena + 13312);     // 128 f32
    float* HsB   = (float*)(arena + 13824);     // 4 * 32*65 f32 = 33280 B
    float* svB   = (float*)(arena + 47104);
    float* sttB  = (float*)(arena + 48128);
    float* sdisB = (float*)(arena + 48640);
    float* sbinvB= (float*)(arena + 49664);     // -> 50688

    const int hbid = 4 * (bid / 5) + (bid % 5) - 1;   // 0..4095
    const int b = hbid * 4 + w;
    float* Hw    = HsB + w * 2080;
    float* sv    = svB + w * 64;
    float* stt   = sttB + w * 32;
    float* sdis  = sdisB + w * 64;
    float* sbinv = sbinvB + w * 64;

    for (int i = tid; i < 6144; i += 256) {
        int k = i >> 6, n = i & 63;
        eWs[n * 104 + k] = (f16)edge_W[i];
    }
    if (tid < 64) swa[tid] = fabsf(wline1[tid]);
    else if (tid < 128) swa[tid] = fabsf(wline2[tid - 64]);
    __syncthreads();

    const float* ub = indiv_us + (size_t)b * (NAG * OBS);

    #pragma unroll
    for (int mt = 0; mt < 2; mt++) {
        f16x8 af[3];
        #pragma unroll
        for (int ks = 0; ks < 3; ks++) {
            const float* up = ub + (mt * 16 + lm) * 96 + ks * 32 + lk * 8;
            float4 v0 = *(const float4*)up;
            float4 v1 = *(const float4*)(up + 4);
            af[ks] = (f16x8){ (f16)v0.x, (f16)v0.y, (f16)v0.z, (f16)v0.w,
                              (f16)v1.x, (f16)v1.y, (f16)v1.z, (f16)v1.w };
        }
        #pragma unroll
        for (int nt = 0; nt < 4; nt++) {
            f32x4 acc = {0.f, 0.f, 0.f, 0.f};
            #pragma unroll
            for (int ks = 0; ks < 3; ks++) {
                f16x8 bb = *(const f16x8*)&eWs[(nt * 16 + lm) * 104 + ks * 32 + lk * 8];
                acc = __builtin_amdgcn_mfma_f32_16x16x32_f16(af[ks], bb, acc, 0, 0, 0);
            }
            int col = nt * 16 + lm;
            float bias = edge_b[col];
            #pragma unroll
            for (int r = 0; r < 4; r++) {
                int row = mt * 16 + lk * 4 + r;
                float hv = acc[r] + bias;
                Hw[row * 65 + col] = hv > 0.f ? hv : 0.f;
            }
        }
    }
    WSYNC();

    float bsum = 0.f;
    #pragma unroll
    for (int n = 0; n < 32; n++) bsum += Hw[n * 65 + l];
    sbinv[l] = bsum > 0.f ? 1.f / bsum : 0.f;

    const int nn = l & 31, half = l >> 5;
    float dd = 0.f;
    #pragma unroll 8
    for (int e = 0; e < 64; e++) dd += Hw[nn * 65 + e] * swa[half * 64 + e];
    float dis = dd > 0.f ? rsqrtf(dd) : 0.f;
    sdis[l] = dis;
    float q = agent_qs[(size_t)b * 32 + nn];
    if (half == 0) stt[nn] = dis * q;
    WSYNC();

    float s1 = 0.f;
    #pragma unroll
    for (int n = 0; n < 32; n++) s1 += Hw[n * 65 + l] * stt[n];
    sv[l] = s1 * swa[l] * sbinv[l];
    WSYNC();

    float y1 = 0.f;
    #pragma unroll 8
    for (int e = 0; e < 64; e++) y1 += Hw[nn * 65 + e] * sv[e];
    float x2 = sdis[nn] * y1;
    if (half == 0) stt[nn] = sdis[32 + nn] * x2;
    WSYNC();

    float s2 = 0.f;
    #pragma unroll
    for (int n = 0; n < 32; n++) s2 += Hw[n * 65 + l] * stt[n];
    sv[l] = s2 * swa[64 + l] * sbinv[l];
    WSYNC();

    float y2 = 0.f;
    #pragma unroll 8
    for (int e = 0; e < 64; e++) y2 += Hw[nn * 65 + e] * sv[e];
    if (half == 0) qs_tot[(size_t)b * 32 + nn] = sdis[32 + nn] * y2;
}

// ======================= K_EP: sum K-half partials + elu mix =======================
__global__ __launch_bounds__(256) void k_ep(
    const float* __restrict__ Pp, const float* __restrict__ qs_tot,
    const float* __restrict__ hw1_b2, const float* __restrict__ hc1_b2,
    const float* __restrict__ hw_b2, const float* __restrict__ hc_b2,
    float* __restrict__ out) {
    const int tid = threadIdx.x;
    const int row = blockIdx.x * 32 + (tid >> 3);
    const int q8 = tid & 7, o = q8 * 4;
    const float* p0 = Pp + (size_t)row * 104;
    const float* p1 = Pp + (size_t)(BATCH + row) * 104;
    f32x4 a0 = *(const f32x4*)(p0 + o);
    f32x4 a1 = *(const f32x4*)(p1 + o);
    f32x4 c0 = *(const f32x4*)(p0 + 32 + o);
    f32x4 c1 = *(const f32x4*)(p1 + 32 + o);
    f32x4 w0 = *(const f32x4*)(p0 + 64 + o);
    f32x4 w1 = *(const f32x4*)(p1 + 64 + o);
    f32x4 qs = *(const f32x4*)(qs_tot + (size_t)row * 32 + o);
    float val = 0.f;
    #pragma unroll
    for (int j = 0; j < 4; j++) {
        float wv1 = fabsf(a0[j] + a1[j] + hw1_b2[o + j]);
        float cv1 = c0[j] + c1[j] + hc1_b2[o + j];
        float wv  = fabsf(w0[j] + w1[j] + hw_b2[o + j]);
        float z = qs[j] * wv1 + cv1;
        float qt = z > 0.f ? z : expm1f(z);
        val += qt * wv;
    }
    val += __shfl_xor(val, 1);
    val += __shfl_xor(val, 2);
    val += __shfl_xor(val, 4);
    if (q8 == 0) out[row] = val + p0[96] + p1[96] + hc_b2[0];
}

// ======================= launch =======================
extern "C" void kernel_launch(void* const* d_in, const int* in_sizes, int n_in,
                              void* d_out, int out_size, void* d_ws, size_t ws_size,
                              hipStream_t stream) {
    const float* agent_qs = (const float*)d_in[0];
    const float* states   = (const float*)d_in[1];
    const float* indiv_us = (const float*)d_in[2];
    const float* edge_W   = (const float*)d_in[3];
    const float* edge_b   = (const float*)d_in[4];
    const float* wline1   = (const float*)d_in[5];
    const float* wline2   = (const float*)d_in[6];
    const float* hw1_w1 = (const float*)d_in[7];
    const float* hw1_b1 = (const float*)d_in[8];
    const float* hw1_w2 = (const float*)d_in[9];
    const float* hw1_b2 = (const float*)d_in[10];
    const float* hc1_w1 = (const float*)d_in[11];
    const float* hc1_b1 = (const float*)d_in[12];
    const float* hc1_w2 = (const float*)d_in[13];
    const float* hc1_b2 = (const float*)d_in[14];
    const float* hw_w1  = (const float*)d_in[15];
    const float* hw_b1  = (const float*)d_in[16];
    const float* hw_w2  = (const float*)d_in[17];
    const float* hw_b2  = (const float*)d_in[18];
    const float* hc_w1  = (const float*)d_in[19];
    const float* hc_b1  = (const float*)d_in[20];
    const float* hc_w2  = (const float*)d_in[21];
    const float* hc_b2  = (const float*)d_in[22];

    char* ws = (char*)d_ws;
    size_t o_qs   = 0;                                       // 2,097,152
    size_t o_W1t  = o_qs + (size_t)BATCH * NAG * 4;          // 2,097,152
    size_t o_b1   = o_W1t + (size_t)NH * SDIM * 2;           // 4096
    size_t o_W2t  = o_b1 + 4096;                             // 49,152
    size_t o_hcw2 = o_W2t + 49152;                           // 512
    size_t o_Pp   = o_hcw2 + 512;                            // 2*16384*104*4

    float* qs_tot   = (float*)(ws + o_qs);
    f16*   W1t      = (f16*)(ws + o_W1t);
    float* b1cat    = (float*)(ws + o_b1);
    f16*   W2t      = (f16*)(ws + o_W2t);
    f16*   hcw2     = (f16*)(ws + o_hcw2);
    float* Pp       = (float*)(ws + o_Pp);

    k_prep<<<NB_PREP, 256, 0, stream>>>(
        hw1_w1, hc1_w1, hw_w1, hc_w1, hw1_b1, hc1_b1, hw_b1, hc_b1,
        hw1_w2, hc1_w2, hw_w2, hc_w2, W1t, b1cat, W2t, hcw2);
    k_main<<<NB_MAIN, 256, 0, stream>>>(
        agent_qs, states, indiv_us, edge_W, edge_b, wline1, wline2,
        W1t, b1cat, W2t, hcw2, qs_tot, Pp);
    k_ep<<<BATCH / 32, 256, 0, stream>>>(Pp, qs_tot, hw1_b2, hc1_b2, hw_b2, hc_b2,
                                         (float*)d_out);
}

// Round 3
// 137.975 us; speedup vs baseline: 1.2438x; 1.2438x over previous
//
#include <hip/hip_runtime.h>
#include <cstdint>

typedef _Float16 f16;
typedef _Float16 f16x2 __attribute__((ext_vector_type(2)));
typedef _Float16 f16x4 __attribute__((ext_vector_type(4)));
typedef _Float16 f16x8 __attribute__((ext_vector_type(8)));
typedef float f32x4 __attribute__((ext_vector_type(4)));

#define AS1U const __attribute__((address_space(1))) unsigned int
#define AS3U __attribute__((address_space(3))) unsigned int

__device__ __forceinline__ void gload_lds16(const void* g, void* l) {
    __builtin_amdgcn_global_load_lds((AS1U*)g, (AS3U*)l, 16, 0, 0);
}

// wave-local LDS sync: HGCN reduction state is per-wave (64 lanes, lockstep)
#define WSYNC() asm volatile("s_waitcnt lgkmcnt(0)" ::: "memory")

#define BATCH 16384
#define NAG   32
#define OBS   96
#define SDIM  1024
#define NE    64
#define HIDN  256
#define NH    1024

// k_front grid layout
#define NB_ST 1024
#define NB_PW 256
#define NB_SM 101
#define NB_HG 4096
#define NB_FRONT (NB_ST + NB_PW + NB_SM + NB_HG)

// ======================= K_FRONT: prep + HGCN in one launch =======================
__global__ __launch_bounds__(256) void k_front(
    const float* __restrict__ agent_qs, const float* __restrict__ states,
    const float* __restrict__ indiv_us, const float* __restrict__ edge_W,
    const float* __restrict__ edge_b, const float* __restrict__ wline1,
    const float* __restrict__ wline2,
    const float* __restrict__ w1a, const float* __restrict__ w1b,
    const float* __restrict__ w1c, const float* __restrict__ w1d,
    const float* __restrict__ b1a, const float* __restrict__ b1b,
    const float* __restrict__ b1c, const float* __restrict__ b1d,
    const float* __restrict__ w2a, const float* __restrict__ w2b,
    const float* __restrict__ w2c, const float* __restrict__ w2d,
    f16* __restrict__ states16, f16* __restrict__ W1t, float* __restrict__ b1cat,
    f16* __restrict__ W2t, f16* __restrict__ hcw2, float* __restrict__ qs_tot) {
    // HGCN arena: eWs 13312 | swa 512 | Hs(f16) 16896 | sv 1024 | stt 512 | sdis 1024 | sbinv 1024
    __shared__ __align__(16) char arena[34304];
    const int tid = threadIdx.x;
    int bid = blockIdx.x;

    if (bid < NB_ST) {                    // states fp32 -> fp16
        int i = bid * 256 + tid;
        const int n4 = BATCH * SDIM / 4;
        const int stride = NB_ST * 256;
        for (; i < n4; i += stride) {
            float4 v = ((const float4*)states)[i];
            f16x4 h = { (f16)v.x, (f16)v.y, (f16)v.z, (f16)v.w };
            ((f16x4*)states16)[i] = h;
        }
        return;
    }
    bid -= NB_ST;
    if (bid < NB_PW) {                    // W1 pack via LDS transpose (coalesced both sides)
        float* tile = (float*)arena;      // [64][65]
        int mlp = bid >> 6, rem = bid & 63, kt = rem >> 2, ct = rem & 3;
        const float* src = (mlp == 0) ? w1a : (mlp == 1) ? w1b : (mlp == 2) ? w1c : w1d;
        int k0 = kt * 64, c0 = ct * 64;
        for (int i = tid; i < 4096; i += 256) {
            int kk = i >> 6, cc = i & 63;
            tile[kk * 65 + cc] = src[(size_t)(k0 + kk) * 256 + c0 + cc];
        }
        __syncthreads();
        for (int i = tid; i < 4096; i += 256) {
            int cc = i >> 6, kk = i & 63;
            W1t[(size_t)(mlp * 256 + c0 + cc) * 1024 + k0 + kk] = (f16)tile[kk * 65 + cc];
        }
        return;
    }
    bid -= NB_PW;
    if (bid < NB_SM) {                    // W2t, hcw2, b1cat
        int i = bid * 256 + tid;
        if (i < 24576) {
            int mp = i >> 13, rem = i & 8191, oo = rem >> 8, kk = rem & 255;
            const float* src = (mp == 0) ? w2a : (mp == 1) ? w2b : w2c;
            W2t[i] = (f16)src[kk * 32 + oo];
        } else if (i < 24832) {
            int k = i - 24576;
            hcw2[k] = (f16)w2d[k];
        } else {                          // i < 25856
            int n = i - 24832;
            int mlp = n >> 8, c = n & 255;
            const float* bsrc = (mlp == 0) ? b1a : (mlp == 1) ? b1b : (mlp == 2) ? b1c : b1d;
            b1cat[n] = bsrc[c];
        }
        return;
    }
    bid -= NB_SM;

    // ---------------- HGCN (H stored f16, stride 66) ----------------
    f16*   eWs   = (f16*)arena;                 // 64*104 f16 = 13312 B
    float* swa   = (float*)(arena + 13312);     // 128 f32
    f16*   HsB   = (f16*)(arena + 13824);       // 4 * 32*66 f16 = 16896 B
    float* svB   = (float*)(arena + 30720);     // 4*64
    float* sttB  = (float*)(arena + 31744);     // 4*32
    float* sdisB = (float*)(arena + 32256);     // 4*64
    float* sbinvB= (float*)(arena + 33280);     // 4*64 -> 34304

    const int w = tid >> 6, l = tid & 63;
    const int b = bid * 4 + w;
    f16*   Hw    = HsB + w * (32 * 66);
    float* sv    = svB + w * 64;
    float* stt   = sttB + w * 32;
    float* sdis  = sdisB + w * 64;
    float* sbinv = sbinvB + w * 64;

    // inline edge_W transpose: edge_W[k][n] -> eWs[n][k] (coalesced global read)
    for (int i = tid; i < 6144; i += 256) {
        int k = i >> 6, n = i & 63;
        eWs[n * 104 + k] = (f16)edge_W[i];
    }
    if (tid < 64) swa[tid] = fabsf(wline1[tid]);
    else if (tid < 128) swa[tid] = fabsf(wline2[tid - 64]);
    __syncthreads();   // the only block-wide barrier (eWs/swa are cross-wave)

    const int lm = l & 15, lk = l >> 4;
    const float* ub = indiv_us + (size_t)b * (NAG * OBS);

    // H = relu(u @ W^T + b): A-frags straight from global (u read exactly once)
    #pragma unroll
    for (int mt = 0; mt < 2; mt++) {
        f16x8 af[3];
        #pragma unroll
        for (int ks = 0; ks < 3; ks++) {
            const float* up = ub + (mt * 16 + lm) * 96 + ks * 32 + lk * 8;
            float4 v0 = *(const float4*)up;
            float4 v1 = *(const float4*)(up + 4);
            af[ks] = (f16x8){ (f16)v0.x, (f16)v0.y, (f16)v0.z, (f16)v0.w,
                              (f16)v1.x, (f16)v1.y, (f16)v1.z, (f16)v1.w };
        }
        #pragma unroll
        for (int nt = 0; nt < 4; nt++) {
            f32x4 acc = {0.f, 0.f, 0.f, 0.f};
            #pragma unroll
            for (int ks = 0; ks < 3; ks++) {
                f16x8 bb = *(const f16x8*)&eWs[(nt * 16 + lm) * 104 + ks * 32 + lk * 8];
                acc = __builtin_amdgcn_mfma_f32_16x16x32_f16(af[ks], bb, acc, 0, 0, 0);
            }
            int col = nt * 16 + lm;
            float bias = edge_b[col];
            #pragma unroll
            for (int r = 0; r < 4; r++) {
                int row = mt * 16 + lk * 4 + r;
                float hv = acc[r] + bias;
                Hw[row * 66 + col] = (f16)(hv > 0.f ? hv : 0.f);
            }
        }
    }
    WSYNC();

    float bsum = 0.f;
    #pragma unroll
    for (int n = 0; n < 32; n++) bsum += (float)Hw[n * 66 + l];
    sbinv[l] = bsum > 0.f ? 1.f / bsum : 0.f;

    const int nn = l & 31, half = l >> 5;
    float dd = 0.f;
    #pragma unroll 8
    for (int e2 = 0; e2 < 32; e2++) {
        f16x2 h2 = *(const f16x2*)&Hw[nn * 66 + e2 * 2];
        dd += (float)h2.x * swa[half * 64 + e2 * 2] + (float)h2.y * swa[half * 64 + e2 * 2 + 1];
    }
    float dis = dd > 0.f ? rsqrtf(dd) : 0.f;
    sdis[l] = dis;
    float q = agent_qs[(size_t)b * 32 + nn];
    if (half == 0) stt[nn] = dis * q;
    WSYNC();

    float s1 = 0.f;
    #pragma unroll
    for (int n = 0; n < 32; n++) s1 += (float)Hw[n * 66 + l] * stt[n];
    sv[l] = s1 * swa[l] * sbinv[l];
    WSYNC();

    float y1 = 0.f;
    #pragma unroll 8
    for (int e2 = 0; e2 < 32; e2++) {
        f16x2 h2 = *(const f16x2*)&Hw[nn * 66 + e2 * 2];
        y1 += (float)h2.x * sv[e2 * 2] + (float)h2.y * sv[e2 * 2 + 1];
    }
    float x2 = sdis[nn] * y1;
    if (half == 0) stt[nn] = sdis[32 + nn] * x2;
    WSYNC();

    float s2 = 0.f;
    #pragma unroll
    for (int n = 0; n < 32; n++) s2 += (float)Hw[n * 66 + l] * stt[n];
    sv[l] = s2 * swa[64 + l] * sbinv[l];
    WSYNC();

    float y2 = 0.f;
    #pragma unroll 8
    for (int e2 = 0; e2 < 32; e2++) {
        f16x2 h2 = *(const f16x2*)&Hw[nn * 66 + e2 * 2];
        y2 += (float)h2.x * sv[e2 * 2] + (float)h2.y * sv[e2 * 2 + 1];
    }
    if (half == 0) qs_tot[(size_t)b * 32 + nn] = sdis[32 + nn] * y2;
}

// ======================= K_GEMM1: layer1 GEMM + fused layer2 partials =======================
__global__ __launch_bounds__(256) void k_gemm1(
    const f16* __restrict__ A, const f16* __restrict__ B,
    const float* __restrict__ b1cat, const f16* __restrict__ W2t,
    const f16* __restrict__ hcw2, float* __restrict__ Pp) {
    __shared__ __align__(16) char smem[33792];
    f16* As = (f16*)smem;                 // [128][64] during K-loop
    f16* Bs = (f16*)(smem + 16384);       // [128][64]
    f16* Ts = (f16*)smem;                 // [128][132] relu'd tile, after K-loop

    const int tid = threadIdx.x;
    const int w = tid >> 6, l = tid & 63;
    // XCD-aware remap: regions of 8mt x 8nt (A 2MB + B 2MB = one XCD L2), 2 regions/XCD
    const int p = blockIdx.x;
    const int xcd = p & 7, slot = p >> 3;
    const int region = slot >> 6, rs = slot & 63;
    const int mt = (xcd * 2 + region) * 8 + (rs >> 3);
    const int nt = rs & 7;
    const int m0 = mt * 128, n0 = nt * 128;
    const int wm = w >> 1, wn = w & 1;
    const int lm = l & 15, lk = l >> 4;
    const int srow = l >> 3;
    const int scol = (l & 7) * 8;

    f32x4 acc[4][4];
    #pragma unroll
    for (int i = 0; i < 4; i++)
        #pragma unroll
        for (int j = 0; j < 4; j++) acc[i][j] = (f32x4){0.f, 0.f, 0.f, 0.f};

    for (int kt = 0; kt < 16; kt++) {
        #pragma unroll
        for (int i = 0; i < 4; i++) {
            int c = w * 4 + i;
            int row = c * 8 + srow;
            gload_lds16(&A[(size_t)(m0 + row) * 1024 + kt * 64 + scol], &As[c * 512]);
            gload_lds16(&B[(size_t)(n0 + row) * 1024 + kt * 64 + scol], &Bs[c * 512]);
        }
        __syncthreads();
        #pragma unroll
        for (int ks = 0; ks < 2; ks++) {
            f16x8 a[4], bb[4];
            #pragma unroll
            for (int i = 0; i < 4; i++)
                a[i] = *(const f16x8*)&As[(wm * 64 + i * 16 + lm) * 64 + ks * 32 + lk * 8];
            #pragma unroll
            for (int j = 0; j < 4; j++)
                bb[j] = *(const f16x8*)&Bs[(wn * 64 + j * 16 + lm) * 64 + ks * 32 + lk * 8];
            #pragma unroll
            for (int i = 0; i < 4; i++)
                #pragma unroll
                for (int j = 0; j < 4; j++)
                    acc[i][j] = __builtin_amdgcn_mfma_f32_16x16x32_f16(a[i], bb[j], acc[i][j], 0, 0, 0);
        }
        __syncthreads();
    }

    // bias + relu -> Ts (f16), C-layout scatter (As/Bs dead after last barrier)
    float bj[4];
    #pragma unroll
    for (int j = 0; j < 4; j++) bj[j] = b1cat[n0 + wn * 64 + j * 16 + lm];
    #pragma unroll
    for (int i = 0; i < 4; i++)
        #pragma unroll
        for (int r = 0; r < 4; r++) {
            int row = wm * 64 + i * 16 + lk * 4 + r;
            #pragma unroll
            for (int j = 0; j < 4; j++) {
                int col = wn * 64 + j * 16 + lm;
                float v = acc[i][j][r] + bj[j];
                Ts[row * 132 + col] = (f16)(v > 0.f ? v : 0.f);
            }
        }
    __syncthreads();

    // fused layer-2 K-half partial: this block's 128 cols = half of MLP (nt>>1)'s K=256
    const int mlp = nt >> 1, kh = nt & 1;
    const int rbase = w * 32;
    if (mlp < 3) {
        const f16* wb = W2t + mlp * 8192 + kh * 128;   // W2t[o][k] rows, k-slice
        f32x4 acc2[2][2];
        acc2[0][0] = (f32x4){0,0,0,0}; acc2[0][1] = (f32x4){0,0,0,0};
        acc2[1][0] = (f32x4){0,0,0,0}; acc2[1][1] = (f32x4){0,0,0,0};
        #pragma unroll
        for (int ks = 0; ks < 4; ks++) {
            f16x8 b0 = *(const f16x8*)&wb[lm * 256 + ks * 32 + lk * 8];
            f16x8 b1 = *(const f16x8*)&wb[(16 + lm) * 256 + ks * 32 + lk * 8];
            #pragma unroll
            for (int i2 = 0; i2 < 2; i2++) {
                f16x8 a = *(const f16x8*)&Ts[(rbase + i2 * 16 + lm) * 132 + ks * 32 + lk * 8];
                acc2[i2][0] = __builtin_amdgcn_mfma_f32_16x16x32_f16(a, b0, acc2[i2][0], 0, 0, 0);
                acc2[i2][1] = __builtin_amdgcn_mfma_f32_16x16x32_f16(a, b1, acc2[i2][1], 0, 0, 0);
            }
        }
        #pragma unroll
        for (int i2 = 0; i2 < 2; i2++)
            #pragma unroll
            for (int j2 = 0; j2 < 2; j2++)
                #pragma unroll
                for (int r = 0; r < 4; r++)
                    Pp[((size_t)kh * BATCH + m0 + rbase + i2 * 16 + lk * 4 + r) * 104
                       + mlp * 32 + j2 * 16 + lm] = acc2[i2][j2][r];
    } else {
        const f16* hc = hcw2 + kh * 128;
        f32x4 acc2[2];
        acc2[0] = (f32x4){0,0,0,0}; acc2[1] = (f32x4){0,0,0,0};
        #pragma unroll
        for (int ks = 0; ks < 4; ks++) {
            f16x8 bz = (f16x8){0,0,0,0,0,0,0,0};
            if (lm == 0) bz = *(const f16x8*)&hc[ks * 32 + lk * 8];
            #pragma unroll
            for (int i2 = 0; i2 < 2; i2++) {
                f16x8 a = *(const f16x8*)&Ts[(rbase + i2 * 16 + lm) * 132 + ks * 32 + lk * 8];
                acc2[i2] = __builtin_amdgcn_mfma_f32_16x16x32_f16(a, bz, acc2[i2], 0, 0, 0);
            }
        }
        if (lm == 0)
            #pragma unroll
            for (int i2 = 0; i2 < 2; i2++)
                #pragma unroll
                for (int r = 0; r < 4; r++)
                    Pp[((size_t)kh * BATCH + m0 + rbase + i2 * 16 + lk * 4 + r) * 104 + 96]
                        = acc2[i2][r];
    }
}

// ======================= K_EP: sum K-half partials + elu mix =======================
__global__ __launch_bounds__(256) void k_ep(
    const float* __restrict__ Pp, const float* __restrict__ qs_tot,
    const float* __restrict__ hw1_b2, const float* __restrict__ hc1_b2,
    const float* __restrict__ hw_b2, const float* __restrict__ hc_b2,
    float* __restrict__ out) {
    const int tid = threadIdx.x;
    const int row = blockIdx.x * 32 + (tid >> 3);
    const int q8 = tid & 7, o = q8 * 4;
    const float* p0 = Pp + (size_t)row * 104;
    const float* p1 = Pp + (size_t)(BATCH + row) * 104;
    f32x4 a0 = *(const f32x4*)(p0 + o);
    f32x4 a1 = *(const f32x4*)(p1 + o);
    f32x4 c0 = *(const f32x4*)(p0 + 32 + o);
    f32x4 c1 = *(const f32x4*)(p1 + 32 + o);
    f32x4 w0 = *(const f32x4*)(p0 + 64 + o);
    f32x4 w1 = *(const f32x4*)(p1 + 64 + o);
    f32x4 qs = *(const f32x4*)(qs_tot + (size_t)row * 32 + o);
    float val = 0.f;
    #pragma unroll
    for (int j = 0; j < 4; j++) {
        float wv1 = fabsf(a0[j] + a1[j] + hw1_b2[o + j]);
        float cv1 = c0[j] + c1[j] + hc1_b2[o + j];
        float wv  = fabsf(w0[j] + w1[j] + hw_b2[o + j]);
        float z = qs[j] * wv1 + cv1;
        float qt = z > 0.f ? z : expm1f(z);
        val += qt * wv;
    }
    val += __shfl_xor(val, 1);
    val += __shfl_xor(val, 2);
    val += __shfl_xor(val, 4);
    if (q8 == 0) out[row] = val + p0[96] + p1[96] + hc_b2[0];
}

// ======================= launch =======================
extern "C" void kernel_launch(void* const* d_in, const int* in_sizes, int n_in,
                              void* d_out, int out_size, void* d_ws, size_t ws_size,
                              hipStream_t stream) {
    const float* agent_qs = (const float*)d_in[0];
    const float* states   = (const float*)d_in[1];
    const float* indiv_us = (const float*)d_in[2];
    const float* edge_W   = (const float*)d_in[3];
    const float* edge_b   = (const float*)d_in[4];
    const float* wline1   = (const float*)d_in[5];
    const float* wline2   = (const float*)d_in[6];
    const float* hw1_w1 = (const float*)d_in[7];
    const float* hw1_b1 = (const float*)d_in[8];
    const float* hw1_w2 = (const float*)d_in[9];
    const float* hw1_b2 = (const float*)d_in[10];
    const float* hc1_w1 = (const float*)d_in[11];
    const float* hc1_b1 = (const float*)d_in[12];
    const float* hc1_w2 = (const float*)d_in[13];
    const float* hc1_b2 = (const float*)d_in[14];
    const float* hw_w1  = (const float*)d_in[15];
    const float* hw_b1  = (const float*)d_in[16];
    const float* hw_w2  = (const float*)d_in[17];
    const float* hw_b2  = (const float*)d_in[18];
    const float* hc_w1  = (const float*)d_in[19];
    const float* hc_b1  = (const float*)d_in[20];
    const float* hc_w2  = (const float*)d_in[21];
    const float* hc_b2  = (const float*)d_in[22];

    char* ws = (char*)d_ws;
    size_t o_states16 = 0;                                   // 33,554,432
    size_t o_qs   = o_states16 + (size_t)BATCH * SDIM * 2;   // 2,097,152
    size_t o_W1t  = o_qs + (size_t)BATCH * NAG * 4;          // 2,097,152
    size_t o_b1   = o_W1t + (size_t)NH * SDIM * 2;           // 4096
    size_t o_W2t  = o_b1 + 4096;                             // 49,152
    size_t o_hcw2 = o_W2t + 49152;                           // 512
    size_t o_Pp   = o_hcw2 + 512;                            // 2*16384*104*4

    f16*   states16 = (f16*)(ws + o_states16);
    float* qs_tot   = (float*)(ws + o_qs);
    f16*   W1t      = (f16*)(ws + o_W1t);
    float* b1cat    = (float*)(ws + o_b1);
    f16*   W2t      = (f16*)(ws + o_W2t);
    f16*   hcw2     = (f16*)(ws + o_hcw2);
    float* Pp       = (float*)(ws + o_Pp);

    k_front<<<NB_FRONT, 256, 0, stream>>>(
        agent_qs, states, indiv_us, edge_W, edge_b, wline1, wline2,
        hw1_w1, hc1_w1, hw_w1, hc_w1, hw1_b1, hc1_b1, hw_b1, hc_b1,
        hw1_w2, hc1_w2, hw_w2, hc_w2,
        states16, W1t, b1cat, W2t, hcw2, qs_tot);
    k_gemm1<<<1024, 256, 0, stream>>>(states16, W1t, b1cat, W2t, hcw2, Pp);
    k_ep<<<BATCH / 32, 256, 0, stream>>>(Pp, qs_tot, hw1_b2, hc1_b2, hw_b2, hc_b2,
                                         (float*)d_out);
}

// Round 4
// 136.522 us; speedup vs baseline: 1.2571x; 1.0106x over previous
//
#include <hip/hip_runtime.h>
#include <cstdint>

typedef _Float16 f16;
typedef _Float16 f16x2 __attribute__((ext_vector_type(2)));
typedef _Float16 f16x4 __attribute__((ext_vector_type(4)));
typedef _Float16 f16x8 __attribute__((ext_vector_type(8)));
typedef float f32x4 __attribute__((ext_vector_type(4)));

#define AS1U const __attribute__((address_space(1))) unsigned int
#define AS3U __attribute__((address_space(3))) unsigned int

__device__ __forceinline__ void gload_lds16(const void* g, void* l) {
    __builtin_amdgcn_global_load_lds((AS1U*)g, (AS3U*)l, 16, 0, 0);
}

// wave-local LDS sync: HGCN reduction state is per-wave (64 lanes, lockstep)
#define WSYNC() asm volatile("s_waitcnt lgkmcnt(0)" ::: "memory")

#define BATCH 16384
#define NAG   32
#define OBS   96
#define SDIM  1024
#define NE    64
#define HIDN  256
#define NH    1024

// k_front grid layout (conv + packs only)
#define NB_ST 1024
#define NB_PW 256
#define NB_SM 101
#define NB_FRONT (NB_ST + NB_PW + NB_SM)

// ======================= K_FRONT: states conv + weight packs =======================
__global__ __launch_bounds__(256) void k_front(
    const float* __restrict__ states,
    const float* __restrict__ w1a, const float* __restrict__ w1b,
    const float* __restrict__ w1c, const float* __restrict__ w1d,
    const float* __restrict__ b1a, const float* __restrict__ b1b,
    const float* __restrict__ b1c, const float* __restrict__ b1d,
    const float* __restrict__ w2a, const float* __restrict__ w2b,
    const float* __restrict__ w2c, const float* __restrict__ w2d,
    f16* __restrict__ states16, f16* __restrict__ W1t, float* __restrict__ b1cat,
    f16* __restrict__ W2t, f16* __restrict__ hcw2) {
    __shared__ float tile[64 * 65];
    const int tid = threadIdx.x;
    int bid = blockIdx.x;

    if (bid < NB_ST) {                    // states fp32 -> fp16
        int i = bid * 256 + tid;
        const int n4 = BATCH * SDIM / 4;
        const int stride = NB_ST * 256;
        for (; i < n4; i += stride) {
            float4 v = ((const float4*)states)[i];
            f16x4 h = { (f16)v.x, (f16)v.y, (f16)v.z, (f16)v.w };
            ((f16x4*)states16)[i] = h;
        }
        return;
    }
    bid -= NB_ST;
    if (bid < NB_PW) {                    // W1 pack via LDS transpose (coalesced both sides)
        int mlp = bid >> 6, rem = bid & 63, kt = rem >> 2, ct = rem & 3;
        const float* src = (mlp == 0) ? w1a : (mlp == 1) ? w1b : (mlp == 2) ? w1c : w1d;
        int k0 = kt * 64, c0 = ct * 64;
        for (int i = tid; i < 4096; i += 256) {
            int kk = i >> 6, cc = i & 63;
            tile[kk * 65 + cc] = src[(size_t)(k0 + kk) * 256 + c0 + cc];
        }
        __syncthreads();
        for (int i = tid; i < 4096; i += 256) {
            int cc = i >> 6, kk = i & 63;
            W1t[(size_t)(mlp * 256 + c0 + cc) * 1024 + k0 + kk] = (f16)tile[kk * 65 + cc];
        }
        return;
    }
    bid -= NB_PW;
    {                                     // W2t, hcw2, b1cat
        int i = bid * 256 + tid;
        if (i < 24576) {
            int mp = i >> 13, rem = i & 8191, oo = rem >> 8, kk = rem & 255;
            const float* src = (mp == 0) ? w2a : (mp == 1) ? w2b : w2c;
            W2t[i] = (f16)src[kk * 32 + oo];
        } else if (i < 24832) {
            int k = i - 24576;
            hcw2[k] = (f16)w2d[k];
        } else if (i < 25856) {
            int n = i - 24832;
            int mlp = n >> 8, c = n & 255;
            const float* bsrc = (mlp == 0) ? b1a : (mlp == 1) ? b1b : (mlp == 2) ? b1c : b1d;
            b1cat[n] = bsrc[c];
        }
    }
}

// ======================= K_GEMM1: layer1 GEMM + fused layer2 partials =======================
__global__ __launch_bounds__(256) void k_gemm1(
    const f16* __restrict__ A, const f16* __restrict__ B,
    const float* __restrict__ b1cat, const f16* __restrict__ W2t,
    const f16* __restrict__ hcw2, float* __restrict__ Pp) {
    __shared__ __align__(16) char smem[33792];
    f16* As = (f16*)smem;                 // [128][64] during K-loop
    f16* Bs = (f16*)(smem + 16384);       // [128][64]
    f16* Ts = (f16*)smem;                 // [128][132] relu'd tile, after K-loop

    const int tid = threadIdx.x;
    const int w = tid >> 6, l = tid & 63;
    // XCD-aware remap: regions of 8mt x 8nt (A 2MB + B 2MB = one XCD L2), 2 regions/XCD
    const int p = blockIdx.x;
    const int xcd = p & 7, slot = p >> 3;
    const int region = slot >> 6, rs = slot & 63;
    const int mt = (xcd * 2 + region) * 8 + (rs >> 3);
    const int nt = rs & 7;
    const int m0 = mt * 128, n0 = nt * 128;
    const int wm = w >> 1, wn = w & 1;
    const int lm = l & 15, lk = l >> 4;
    const int srow = l >> 3;
    const int scol = (l & 7) * 8;

    f32x4 acc[4][4];
    #pragma unroll
    for (int i = 0; i < 4; i++)
        #pragma unroll
        for (int j = 0; j < 4; j++) acc[i][j] = (f32x4){0.f, 0.f, 0.f, 0.f};

    for (int kt = 0; kt < 16; kt++) {
        #pragma unroll
        for (int i = 0; i < 4; i++) {
            int c = w * 4 + i;
            int row = c * 8 + srow;
            gload_lds16(&A[(size_t)(m0 + row) * 1024 + kt * 64 + scol], &As[c * 512]);
            gload_lds16(&B[(size_t)(n0 + row) * 1024 + kt * 64 + scol], &Bs[c * 512]);
        }
        __syncthreads();
        #pragma unroll
        for (int ks = 0; ks < 2; ks++) {
            f16x8 a[4], bb[4];
            #pragma unroll
            for (int i = 0; i < 4; i++)
                a[i] = *(const f16x8*)&As[(wm * 64 + i * 16 + lm) * 64 + ks * 32 + lk * 8];
            #pragma unroll
            for (int j = 0; j < 4; j++)
                bb[j] = *(const f16x8*)&Bs[(wn * 64 + j * 16 + lm) * 64 + ks * 32 + lk * 8];
            #pragma unroll
            for (int i = 0; i < 4; i++)
                #pragma unroll
                for (int j = 0; j < 4; j++)
                    acc[i][j] = __builtin_amdgcn_mfma_f32_16x16x32_f16(a[i], bb[j], acc[i][j], 0, 0, 0);
        }
        __syncthreads();
    }

    // bias + relu -> Ts (f16), C-layout scatter (As/Bs dead after last barrier)
    float bj[4];
    #pragma unroll
    for (int j = 0; j < 4; j++) bj[j] = b1cat[n0 + wn * 64 + j * 16 + lm];
    #pragma unroll
    for (int i = 0; i < 4; i++)
        #pragma unroll
        for (int r = 0; r < 4; r++) {
            int row = wm * 64 + i * 16 + lk * 4 + r;
            #pragma unroll
            for (int j = 0; j < 4; j++) {
                int col = wn * 64 + j * 16 + lm;
                float v = acc[i][j][r] + bj[j];
                Ts[row * 132 + col] = (f16)(v > 0.f ? v : 0.f);
            }
        }
    __syncthreads();

    // fused layer-2 K-half partial: this block's 128 cols = half of MLP (nt>>1)'s K=256
    const int mlp = nt >> 1, kh = nt & 1;
    const int rbase = w * 32;
    if (mlp < 3) {
        const f16* wb = W2t + mlp * 8192 + kh * 128;   // W2t[o][k] rows, k-slice
        f32x4 acc2[2][2];
        acc2[0][0] = (f32x4){0,0,0,0}; acc2[0][1] = (f32x4){0,0,0,0};
        acc2[1][0] = (f32x4){0,0,0,0}; acc2[1][1] = (f32x4){0,0,0,0};
        #pragma unroll
        for (int ks = 0; ks < 4; ks++) {
            f16x8 b0 = *(const f16x8*)&wb[lm * 256 + ks * 32 + lk * 8];
            f16x8 b1 = *(const f16x8*)&wb[(16 + lm) * 256 + ks * 32 + lk * 8];
            #pragma unroll
            for (int i2 = 0; i2 < 2; i2++) {
                f16x8 a = *(const f16x8*)&Ts[(rbase + i2 * 16 + lm) * 132 + ks * 32 + lk * 8];
                acc2[i2][0] = __builtin_amdgcn_mfma_f32_16x16x32_f16(a, b0, acc2[i2][0], 0, 0, 0);
                acc2[i2][1] = __builtin_amdgcn_mfma_f32_16x16x32_f16(a, b1, acc2[i2][1], 0, 0, 0);
            }
        }
        #pragma unroll
        for (int i2 = 0; i2 < 2; i2++)
            #pragma unroll
            for (int j2 = 0; j2 < 2; j2++)
                #pragma unroll
                for (int r = 0; r < 4; r++)
                    Pp[((size_t)kh * BATCH + m0 + rbase + i2 * 16 + lk * 4 + r) * 104
                       + mlp * 32 + j2 * 16 + lm] = acc2[i2][j2][r];
    } else {
        const f16* hc = hcw2 + kh * 128;
        f32x4 acc2[2];
        acc2[0] = (f32x4){0,0,0,0}; acc2[1] = (f32x4){0,0,0,0};
        #pragma unroll
        for (int ks = 0; ks < 4; ks++) {
            f16x8 bz = (f16x8){0,0,0,0,0,0,0,0};
            if (lm == 0) bz = *(const f16x8*)&hc[ks * 32 + lk * 8];
            #pragma unroll
            for (int i2 = 0; i2 < 2; i2++) {
                f16x8 a = *(const f16x8*)&Ts[(rbase + i2 * 16 + lm) * 132 + ks * 32 + lk * 8];
                acc2[i2] = __builtin_amdgcn_mfma_f32_16x16x32_f16(a, bz, acc2[i2], 0, 0, 0);
            }
        }
        if (lm == 0)
            #pragma unroll
            for (int i2 = 0; i2 < 2; i2++)
                #pragma unroll
                for (int r = 0; r < 4; r++)
                    Pp[((size_t)kh * BATCH + m0 + rbase + i2 * 16 + lk * 4 + r) * 104 + 96]
                        = acc2[i2][r];
    }
}

// ======================= K_HGCN_EP: HGCN + fused mix epilogue =======================
__global__ __launch_bounds__(256, 5) void k_hgcn_ep(
    const float* __restrict__ agent_qs, const float* __restrict__ indiv_us,
    const float* __restrict__ edge_W, const float* __restrict__ edge_b,
    const float* __restrict__ wline1, const float* __restrict__ wline2,
    const float* __restrict__ Pp,
    const float* __restrict__ hw1_b2, const float* __restrict__ hc1_b2,
    const float* __restrict__ hw_b2, const float* __restrict__ hc_b2,
    float* __restrict__ out) {
    // arena: eWs 13312 | swa 512 | Hs(f16) 16896 | sv16 512 | stt16 256 | sdis16 512 | sbinv16 512 = 32512
    __shared__ __align__(16) char arena[32512];
    f16*   eWs   = (f16*)arena;
    float* swa   = (float*)(arena + 13312);
    f16*   HsB   = (f16*)(arena + 13824);
    f16*   svB   = (f16*)(arena + 30720);
    f16*   sttB  = (f16*)(arena + 31232);
    f16*   sdisB = (f16*)(arena + 31488);
    f16*   sbinvB= (f16*)(arena + 32000);

    const int tid = threadIdx.x;
    const int w = tid >> 6, l = tid & 63;
    const int b = blockIdx.x * 4 + w;
    f16* Hw    = HsB + w * (32 * 66);
    f16* sv    = svB + w * 64;
    f16* stt   = sttB + w * 32;
    f16* sdis  = sdisB + w * 64;
    f16* sbinv = sbinvB + w * 64;

    const int nn = l & 31, half = l >> 5;

    // T14: issue epilogue loads early (lanes 0-31), consume after y2
    float pa0 = 0.f, pa1 = 0.f, pc0 = 0.f, pc1 = 0.f, pw0 = 0.f, pw1 = 0.f;
    float p96a = 0.f, p96b = 0.f, bw1 = 0.f, bc1 = 0.f, bww = 0.f, bhc = 0.f;
    if (half == 0) {
        const float* p0 = Pp + (size_t)b * 104;
        const float* p1 = Pp + (size_t)(BATCH + b) * 104;
        pa0 = p0[nn];      pa1 = p1[nn];
        pc0 = p0[32 + nn]; pc1 = p1[32 + nn];
        pw0 = p0[64 + nn]; pw1 = p1[64 + nn];
        p96a = p0[96];     p96b = p1[96];
        bw1 = hw1_b2[nn];  bc1 = hc1_b2[nn];
        bww = hw_b2[nn];   bhc = hc_b2[0];
    }
    float q = agent_qs[(size_t)b * 32 + nn];

    // inline edge_W transpose: edge_W[k][n] -> eWs[n][k] (coalesced global read)
    for (int i = tid; i < 6144; i += 256) {
        int k = i >> 6, n = i & 63;
        eWs[n * 104 + k] = (f16)edge_W[i];
    }
    if (tid < 64) swa[tid] = fabsf(wline1[tid]);
    else if (tid < 128) swa[tid] = fabsf(wline2[tid - 64]);
    __syncthreads();   // the only block-wide barrier (eWs/swa are cross-wave)

    const int lm = l & 15, lk = l >> 4;
    const float* ub = indiv_us + (size_t)b * (NAG * OBS);

    // H = relu(u @ W^T + b): A-frags straight from global (u read exactly once)
    #pragma unroll
    for (int mt = 0; mt < 2; mt++) {
        f16x8 af[3];
        #pragma unroll
        for (int ks = 0; ks < 3; ks++) {
            const float* up = ub + (mt * 16 + lm) * 96 + ks * 32 + lk * 8;
            float4 v0 = *(const float4*)up;
            float4 v1 = *(const float4*)(up + 4);
            af[ks] = (f16x8){ (f16)v0.x, (f16)v0.y, (f16)v0.z, (f16)v0.w,
                              (f16)v1.x, (f16)v1.y, (f16)v1.z, (f16)v1.w };
        }
        #pragma unroll
        for (int nt = 0; nt < 4; nt++) {
            f32x4 acc = {0.f, 0.f, 0.f, 0.f};
            #pragma unroll
            for (int ks = 0; ks < 3; ks++) {
                f16x8 bb = *(const f16x8*)&eWs[(nt * 16 + lm) * 104 + ks * 32 + lk * 8];
                acc = __builtin_amdgcn_mfma_f32_16x16x32_f16(af[ks], bb, acc, 0, 0, 0);
            }
            int col = nt * 16 + lm;
            float bias = edge_b[col];
            #pragma unroll
            for (int r = 0; r < 4; r++) {
                int row = mt * 16 + lk * 4 + r;
                float hv = acc[r] + bias;
                Hw[row * 66 + col] = (f16)(hv > 0.f ? hv : 0.f);
            }
        }
    }
    WSYNC();

    float bsum = 0.f;
    #pragma unroll
    for (int n = 0; n < 32; n++) bsum += (float)Hw[n * 66 + l];
    sbinv[l] = (f16)(bsum > 0.f ? 1.f / bsum : 0.f);

    float dd = 0.f;
    #pragma unroll 8
    for (int e2 = 0; e2 < 32; e2++) {
        f16x2 h2 = *(const f16x2*)&Hw[nn * 66 + e2 * 2];
        dd += (float)h2.x * swa[half * 64 + e2 * 2] + (float)h2.y * swa[half * 64 + e2 * 2 + 1];
    }
    float dis = dd > 0.f ? rsqrtf(dd) : 0.f;
    sdis[l] = (f16)dis;
    if (half == 0) stt[nn] = (f16)(dis * q);
    WSYNC();

    float s1 = 0.f;
    #pragma unroll
    for (int n = 0; n < 32; n++) s1 += (float)Hw[n * 66 + l] * (float)stt[n];
    sv[l] = (f16)(s1 * swa[l] * (float)sbinv[l]);
    WSYNC();

    float y1 = 0.f;
    #pragma unroll 8
    for (int e2 = 0; e2 < 32; e2++) {
        f16x2 h2 = *(const f16x2*)&Hw[nn * 66 + e2 * 2];
        f16x2 s2v = *(const f16x2*)&sv[e2 * 2];
        y1 += (float)h2.x * (float)s2v.x + (float)h2.y * (float)s2v.y;
    }
    float x2 = (float)sdis[nn] * y1;
    if (half == 0) stt[nn] = (f16)((float)sdis[32 + nn] * x2);
    WSYNC();

    float s2 = 0.f;
    #pragma unroll
    for (int n = 0; n < 32; n++) s2 += (float)Hw[n * 66 + l] * (float)stt[n];
    sv[l] = (f16)(s2 * swa[64 + l] * (float)sbinv[l]);
    WSYNC();

    float y2 = 0.f;
    #pragma unroll 8
    for (int e2 = 0; e2 < 32; e2++) {
        f16x2 h2 = *(const f16x2*)&Hw[nn * 66 + e2 * 2];
        f16x2 s2v = *(const f16x2*)&sv[e2 * 2];
        y2 += (float)h2.x * (float)s2v.x + (float)h2.y * (float)s2v.y;
    }

    // ---- fused mix epilogue (lanes 0-31 of each wave) ----
    float qsv = (float)sdis[32 + nn] * y2;
    float w1v = fabsf(pa0 + pa1 + bw1);
    float c1v = pc0 + pc1 + bc1;
    float wwv = fabsf(pw0 + pw1 + bww);
    float z = qsv * w1v + c1v;
    float qt = z > 0.f ? z : expm1f(z);
    float val = (half == 0) ? qt * wwv : 0.f;
    val += __shfl_xor(val, 1, 32);
    val += __shfl_xor(val, 2, 32);
    val += __shfl_xor(val, 4, 32);
    val += __shfl_xor(val, 8, 32);
    val += __shfl_xor(val, 16, 32);
    if (l == 0) out[b] = val + p96a + p96b + bhc;
}

// ======================= launch =======================
extern "C" void kernel_launch(void* const* d_in, const int* in_sizes, int n_in,
                              void* d_out, int out_size, void* d_ws, size_t ws_size,
                              hipStream_t stream) {
    const float* agent_qs = (const float*)d_in[0];
    const float* states   = (const float*)d_in[1];
    const float* indiv_us = (const float*)d_in[2];
    const float* edge_W   = (const float*)d_in[3];
    const float* edge_b   = (const float*)d_in[4];
    const float* wline1   = (const float*)d_in[5];
    const float* wline2   = (const float*)d_in[6];
    const float* hw1_w1 = (const float*)d_in[7];
    const float* hw1_b1 = (const float*)d_in[8];
    const float* hw1_w2 = (const float*)d_in[9];
    const float* hw1_b2 = (const float*)d_in[10];
    const float* hc1_w1 = (const float*)d_in[11];
    const float* hc1_b1 = (const float*)d_in[12];
    const float* hc1_w2 = (const float*)d_in[13];
    const float* hc1_b2 = (const float*)d_in[14];
    const float* hw_w1  = (const float*)d_in[15];
    const float* hw_b1  = (const float*)d_in[16];
    const float* hw_w2  = (const float*)d_in[17];
    const float* hw_b2  = (const float*)d_in[18];
    const float* hc_w1  = (const float*)d_in[19];
    const float* hc_b1  = (const float*)d_in[20];
    const float* hc_w2  = (const float*)d_in[21];
    const float* hc_b2  = (const float*)d_in[22];

    char* ws = (char*)d_ws;
    size_t o_states16 = 0;                                   // 33,554,432
    size_t o_W1t  = o_states16 + (size_t)BATCH * SDIM * 2;   // 2,097,152
    size_t o_b1   = o_W1t + (size_t)NH * SDIM * 2;           // 4096
    size_t o_W2t  = o_b1 + 4096;                             // 49,152
    size_t o_hcw2 = o_W2t + 49152;                           // 512
    size_t o_Pp   = o_hcw2 + 512;                            // 2*16384*104*4

    f16*   states16 = (f16*)(ws + o_states16);
    f16*   W1t      = (f16*)(ws + o_W1t);
    float* b1cat    = (float*)(ws + o_b1);
    f16*   W2t      = (f16*)(ws + o_W2t);
    f16*   hcw2     = (f16*)(ws + o_hcw2);
    float* Pp       = (float*)(ws + o_Pp);

    k_front<<<NB_FRONT, 256, 0, stream>>>(
        states,
        hw1_w1, hc1_w1, hw_w1, hc_w1, hw1_b1, hc1_b1, hw_b1, hc_b1,
        hw1_w2, hc1_w2, hw_w2, hc_w2,
        states16, W1t, b1cat, W2t, hcw2);
    k_gemm1<<<1024, 256, 0, stream>>>(states16, W1t, b1cat, W2t, hcw2, Pp);
    k_hgcn_ep<<<BATCH / 4, 256, 0, stream>>>(
        agent_qs, indiv_us, edge_W, edge_b, wline1, wline2, Pp,
        hw1_b2, hc1_b2, hw_b2, hc_b2, (float*)d_out);
}